// Round 13
// baseline (79.545 us; speedup 1.0000x reference)
//
#include <hip/hip_runtime.h>

typedef __attribute__((ext_vector_type(8))) short short8;
typedef __attribute__((ext_vector_type(4))) float f32x4;

#define KPAD 40     // gates kernel B chunk row: 32 data + 8 pad shorts

// workspace layout (bytes)
#define WS_HID 0u        // 256*256 f32  = 262144
#define WS_CTX 262144u   // 65536 f32    = 262144
#define WS_WBF 524288u   // 8192 x 16B   = 131072 (ends 655360)

__device__ __forceinline__ unsigned cvtpk(float lo, float hi) {
    unsigned r;
    asm("v_cvt_pk_bf16_f32 %0, %1, %2" : "=v"(r) : "v"(lo), "v"(hi));
    return r;
}
__device__ __forceinline__ int4 pack8(float4 x0, float4 x1) {
    int4 q;
    q.x = (int)cvtpk(x0.x, x0.y);
    q.y = (int)cvtpk(x0.z, x0.w);
    q.z = (int)cvtpk(x1.x, x1.y);
    q.w = (int)cvtpk(x1.z, x1.w);
    return q;
}
__device__ __forceinline__ float bf2f(unsigned s) {
    union { float f; unsigned u; } v; v.u = s << 16;
    return v.f;
}
__device__ __forceinline__ float tanh_fast(float x) {
    float e2 = __expf(2.f * x);
    return 1.f - 2.f * __builtin_amdgcn_rcpf(e2 + 1.f);
}
__device__ __forceinline__ float sigmoid_fast(float x) {
    return __builtin_amdgcn_rcpf(1.f + __expf(-x));
}
__device__ __forceinline__ void gload16(const void* g, void* l) {
    __builtin_amdgcn_global_load_lds((const __attribute__((address_space(1))) void*)g,
                                     (__attribute__((address_space(3))) void*)l, 16, 0, 0);
}

// ---------------- K0: hid GEMV + W_i2h -> frag-order bf16 ----------------
// Wbf unit u (16B): u = cf*512 + ks*64 + lane holds bf16 of
// W_i2h[n = cf*16 + (lane&15)][k = ks*32 + (lane>>4)*8 .. +8]
__global__ __launch_bounds__(256) void k_prep(
    const float* __restrict__ prev_h, const float* __restrict__ W_i2h,
    const float* __restrict__ W_h2h, const float* __restrict__ b_h2h,
    float* __restrict__ hid, int4* __restrict__ Wbf)
{
    int bid = blockIdx.x, tid = threadIdx.x;
    if (bid < 256) {                       // hid[b][h] = prev_h[b]·W_h2h[h] + b_h2h[h]
        __shared__ float ph[256];
        ph[tid] = prev_h[bid * 256 + tid];
        __syncthreads();
        float acc = b_h2h[tid];
        const float4* w = (const float4*)(W_h2h + tid * 256);
        #pragma unroll 8
        for (int k4 = 0; k4 < 64; ++k4) {
            float4 ww = w[k4];
            acc += ww.x * ph[k4*4+0] + ww.y * ph[k4*4+1] + ww.z * ph[k4*4+2] + ww.w * ph[k4*4+3];
        }
        hid[bid * 256 + tid] = acc;
    } else {                               // frag-order convert: 8192 units
        int u = (bid - 256) * 256 + tid;
        int cf = u >> 9, ks = (u >> 6) & 7;
        int n = cf * 16 + (u & 15);
        int k0 = ks * 32 + ((u >> 4) & 3) * 8;
        float4 x0 = *(const float4*)(W_i2h + n * 256 + k0);
        float4 x1 = *(const float4*)(W_i2h + n * 256 + k0 + 4);
        Wbf[u] = pack8(x0, x1);
    }
}

// ---------------- K1: FUSED attention: e -> p -> Z -> alpha, ctx ----------------
// 256 blocks (block = batch b) x 512 thr (8 waves). B (128KB frag-order) in LDS once.
// Waves free-run 4 tiles of 16 bt-rows, ZERO barriers in the loop. A-loads pinned
// via volatile asm. REGISTER DIET vs R12 (which spilled at VGPR=128, 21.8MB scratch):
// ctx accumulates via per-tile shfl-reduce + wave-private LDS RMW (no ctxacc[64]);
// p goes to LDS pls[] (no p4[4][4]). Demand ~125 arch VGPR -> fits the 128 cap.
__global__ __launch_bounds__(512, 2) void k_attn(
    const float* __restrict__ BH, const int4* __restrict__ Wbf,
    const float* __restrict__ hid, const float* __restrict__ Wsc,
    float* __restrict__ alpha, float* __restrict__ ctx)
{
    __shared__ short Blds[65536];          // 128 KB frag-order B panel
    __shared__ float hdl[256], wscl[256];
    __shared__ float pl8[8][16];           // per-wave row-p exchange (current tile)
    __shared__ float pls[32][16];          // p for all 512 rows (alpha epilogue)
    __shared__ float r8[8][256];           // per-wave ctx accumulators
    __shared__ float zsh[8];

    const int tid = threadIdx.x;
    const int lane = tid & 63;
    const int w8 = tid >> 6;               // wave 0..7
    const int l15 = lane & 15, lg = lane >> 4;
    const int b = blockIdx.x;

    int4 la[16];
    #define ISSUE_A(tile_)                                                          \
        {                                                                           \
            const float* base_ = BH + ((size_t)b * 512 + (tile_) * 16 + l15) * 256  \
                                 + lg * 8;                                          \
            asm volatile(                                                           \
                "global_load_dwordx4 %0, %16, off offset:0\n"                       \
                "global_load_dwordx4 %1, %16, off offset:16\n"                      \
                "global_load_dwordx4 %2, %16, off offset:128\n"                     \
                "global_load_dwordx4 %3, %16, off offset:144\n"                     \
                "global_load_dwordx4 %4, %16, off offset:256\n"                     \
                "global_load_dwordx4 %5, %16, off offset:272\n"                     \
                "global_load_dwordx4 %6, %16, off offset:384\n"                     \
                "global_load_dwordx4 %7, %16, off offset:400\n"                     \
                "global_load_dwordx4 %8, %16, off offset:512\n"                     \
                "global_load_dwordx4 %9, %16, off offset:528\n"                     \
                "global_load_dwordx4 %10, %16, off offset:640\n"                    \
                "global_load_dwordx4 %11, %16, off offset:656\n"                    \
                "global_load_dwordx4 %12, %16, off offset:768\n"                    \
                "global_load_dwordx4 %13, %16, off offset:784\n"                    \
                "global_load_dwordx4 %14, %16, off offset:896\n"                    \
                "global_load_dwordx4 %15, %16, off offset:912\n"                    \
                : "=v"(la[0]), "=v"(la[1]), "=v"(la[2]), "=v"(la[3]),               \
                  "=v"(la[4]), "=v"(la[5]), "=v"(la[6]), "=v"(la[7]),               \
                  "=v"(la[8]), "=v"(la[9]), "=v"(la[10]), "=v"(la[11]),             \
                  "=v"(la[12]), "=v"(la[13]), "=v"(la[14]), "=v"(la[15])            \
                : "v"(base_));                                                      \
        }

    ISSUE_A(w8);                           // tile 0 in flight

    // B panel DMA: 16 rounds x 8KB
    {
        const char* g = (const char*)Wbf;
        #pragma unroll
        for (int rnd = 0; rnd < 16; ++rnd)
            gload16(g + rnd * 8192 + tid * 16, (char*)Blds + rnd * 8192 + tid * 16);
    }
    if (tid < 256) { hdl[tid] = hid[b * 256 + tid]; wscl[tid] = Wsc[tid]; }
    // zero ctx accumulators
    ((float4*)r8)[tid] = (float4){0.f, 0.f, 0.f, 0.f};
    __syncthreads();                       // drains B DMA + tile-0 A loads

    float zacc = 0.f;

    #pragma unroll
    for (int ti = 0; ti < 4; ++ti) {
        const int tile = ti * 8 + w8;
        asm volatile("s_waitcnt vmcnt(0)" ::: "memory");
        __builtin_amdgcn_sched_barrier(0);
        short8 af[8];
        #pragma unroll
        for (int ks = 0; ks < 8; ++ks) {
            float4 f0, f1;
            *(int4*)&f0 = la[2 * ks];
            *(int4*)&f1 = la[2 * ks + 1];
            *(int4*)&af[ks] = pack8(f0, f1);
        }
        if (ti < 3) ISSUE_A(tile + 8);     // volatile: issues HERE, flies under MFMA

        float esum[4] = {0.f, 0.f, 0.f, 0.f};
        #pragma unroll
        for (int h2 = 0; h2 < 2; ++h2) {   // col halves -> acc only 32 regs (AGPR)
            f32x4 acc[8];
            #pragma unroll
            for (int c = 0; c < 8; ++c) acc[c] = (f32x4){0.f, 0.f, 0.f, 0.f};
            #pragma unroll
            for (int ks = 0; ks < 8; ++ks)
                #pragma unroll
                for (int c = 0; c < 8; ++c)
                    acc[c] = __builtin_amdgcn_mfma_f32_16x16x32_bf16(af[ks],
                        *(const short8*)&Blds[(((h2 * 8 + c) * 512) + ks * 64 + lane) * 8],
                        acc[c], 0, 0, 0);
            #pragma unroll
            for (int c = 0; c < 8; ++c) {
                int col = (h2 * 8 + c) * 16 + l15;
                float wv = wscl[col], hv = hdl[col];
                #pragma unroll
                for (int r = 0; r < 4; ++r)
                    esum[r] += wv * tanh_fast(acc[c][r] + hv);
            }
        }
        #pragma unroll
        for (int r = 0; r < 4; ++r) {
            float s = esum[r];
            s += __shfl_xor(s, 1); s += __shfl_xor(s, 2);
            s += __shfl_xor(s, 4); s += __shfl_xor(s, 8);
            esum[r] = s;                   // e[tile*16 + lg*4 + r]
        }
        float ps = 0.f;
        #pragma unroll
        for (int r = 0; r < 4; ++r) {
            float pr = __expf(esum[r]);    // |e| <= ||Wsc||_1 ~ 10.2: shift-free safe
            ps += pr;
            esum[r] = pr;
        }
        ps += __shfl_xor(ps, 16); ps += __shfl_xor(ps, 32);
        zacc += ps;
        if (l15 == 0) {
            #pragma unroll
            for (int r = 0; r < 4; ++r) {
                pl8[w8][lg * 4 + r] = esum[r];
                pls[tile][lg * 4 + r] = esum[r];
            }
        }
        float pv = pl8[w8][l15];           // same-wave LDS dep -> auto lgkmcnt
        // ctx accumulate: reduce pv*A over the 16 rows (l15 lanes), RMW into r8[w8]
        #pragma unroll
        for (int ks = 0; ks < 8; ++ks) {
            float v[8];
            #pragma unroll
            for (int j = 0; j < 8; ++j) {
                v[j] = pv * bf2f((unsigned)(unsigned short)af[ks][j]);
                v[j] += __shfl_xor(v[j], 1); v[j] += __shfl_xor(v[j], 2);
                v[j] += __shfl_xor(v[j], 4); v[j] += __shfl_xor(v[j], 8);
            }
            if (l15 == 0) {
                #pragma unroll
                for (int j = 0; j < 8; ++j)
                    r8[w8][ks * 32 + lg * 8 + j] += v[j];
            }
        }
    }

    if (lane == 0) zsh[w8] = zacc;
    __syncthreads();
    float Z = 0.f;
    #pragma unroll
    for (int i = 0; i < 8; ++i) Z += zsh[i];
    const float inv = 1.f / Z;
    if (tid < 256) {
        alpha[b * 512 + tid]       = pls[tid >> 4][tid & 15] * inv;
        alpha[b * 512 + 256 + tid] = pls[16 + (tid >> 4)][tid & 15] * inv;
        float s = 0.f;
        #pragma unroll
        for (int ww = 0; ww < 8; ++ww) s += r8[ww][tid];
        ctx[b * 256 + tid] = s * inv;
    }
    #undef ISSUE_A
}

// ---------------- K2: gates GEMM (256x1024, K=608=19x32) fused with LSTM ----------------
__global__ __launch_bounds__(256) void k_gates_lstm(
    const float* __restrict__ ctx, const float* __restrict__ onehot,
    const float* __restrict__ prev_h, const float* __restrict__ W_ih,
    const float* __restrict__ W_hh, const float* __restrict__ b_ih,
    const float* __restrict__ b_hh, const float* __restrict__ prev_c,
    float* __restrict__ out)
{
    __shared__ char smem[20800];
    short* AlB = (short*)smem;            // [2][64*KPAD]
    short* BlB = (short*)smem + 5120;     // [2][64*KPAD]
    const int tid = threadIdx.x;
    const int lane = tid & 63;
    const int w = tid >> 6;
    const int l15 = lane & 15, lg = lane >> 4;
    const int rb = blockIdx.x * 64;
    const int hb = blockIdx.y;

    f32x4 acc[4];
    #pragma unroll
    for (int j = 0; j < 4; j++) acc[j] = (f32x4){0.f, 0.f, 0.f, 0.f};

    const int arow = tid >> 2, akg = tid & 3;
    const int rg = rb + arow;
    const int bn = tid >> 2, bq = tid & 3;
    const int np_ = hb * 64 + bn, hh_ = np_ >> 2, gg_ = np_ & 3;
    const float* wih_row = W_ih + (size_t)(gg_ * 256 + hh_) * 352;
    const float* whh_row = W_hh + (size_t)(gg_ * 256 + hh_) * 256;

    auto stageAB = [&](int kc, int bu) {
        int k0 = kc * 32 + akg * 8;
        const float4* pa;
        if (k0 < 256)      pa = (const float4*)(ctx    + rg * 256 + k0);
        else if (k0 < 352) pa = (const float4*)(onehot + rg * 96  + (k0 - 256));
        else               pa = (const float4*)(prev_h + rg * 256 + (k0 - 352));
        float4 x0 = pa[0], x1 = pa[1];
        *(int4*)&AlB[bu * 2560 + arow * KPAD + akg * 8] = pack8(x0, x1);
        int kb = kc * 32 + bq * 8;
        const float* pb = (kb < 352) ? (wih_row + kb) : (whh_row + (kb - 352));
        float4 y0 = *(const float4*)pb, y1 = *(const float4*)(pb + 4);
        *(int4*)&BlB[bu * 2560 + bn * KPAD + bq * 8] = pack8(y0, y1);
    };

    stageAB(0, 0);
    __syncthreads();

    for (int kc = 0; kc < 19; ++kc) {
        int cur = kc & 1;
        short8 af = *(const short8*)&AlB[cur * 2560 + (w * 16 + l15) * KPAD + lg * 8];
        short8 bfr[4];
        #pragma unroll
        for (int cf = 0; cf < 4; cf++)
            bfr[cf] = *(const short8*)&BlB[cur * 2560 + (cf * 16 + l15) * KPAD + lg * 8];
        if (kc < 18) stageAB(kc + 1, cur ^ 1);
        #pragma unroll
        for (int cf = 0; cf < 4; cf++)
            acc[cf] = __builtin_amdgcn_mfma_f32_16x16x32_bf16(af, bfr[cf], acc[cf], 0, 0, 0);
        __syncthreads();
    }

    float* Gt = (float*)smem;                    // [64][65]
    #pragma unroll
    for (int cf = 0; cf < 4; cf++) {
        int col = cf * 16 + l15;
        int np = hb * 64 + col;
        int hg = np >> 2, g = np & 3;
        float bias = b_ih[g * 256 + hg] + b_hh[g * 256 + hg];
        #pragma unroll
        for (int r = 0; r < 4; r++)
            Gt[(w * 16 + lg * 4 + r) * 65 + col] = acc[cf][r] + bias;
    }
    __syncthreads();

    #pragma unroll
    for (int it = 0; it < 4; ++it) {
        int elem = it * 256 + tid;               // < 1024
        int row = elem >> 4, hl = elem & 15;
        float gi = Gt[row * 65 + hl * 4 + 0];
        float gf = Gt[row * 65 + hl * 4 + 1];
        float gg = Gt[row * 65 + hl * 4 + 2];
        float go = Gt[row * 65 + hl * 4 + 3];
        int bg = rb + row, hglob = hb * 16 + hl;
        float cv = sigmoid_fast(gf) * prev_c[bg * 256 + hglob] + sigmoid_fast(gi) * tanh_fast(gg);
        out[bg * 256 + hglob] = sigmoid_fast(go) * tanh_fast(cv);
        out[65536 + bg * 256 + hglob] = cv;
    }
}

extern "C" void kernel_launch(void* const* d_in, const int* in_sizes, int n_in,
                              void* d_out, int out_size, void* d_ws, size_t ws_size,
                              hipStream_t stream) {
    (void)in_sizes; (void)n_in; (void)out_size; (void)ws_size;
    const float* prev_h  = (const float*)d_in[0];
    const float* prev_c  = (const float*)d_in[1];
    const float* batch_H = (const float*)d_in[2];
    const float* onehot  = (const float*)d_in[3];
    const float* W_i2h   = (const float*)d_in[4];
    const float* W_h2h   = (const float*)d_in[5];
    const float* b_h2h   = (const float*)d_in[6];
    const float* W_score = (const float*)d_in[7];
    const float* W_ih    = (const float*)d_in[8];
    const float* W_hh    = (const float*)d_in[9];
    const float* b_ih    = (const float*)d_in[10];
    const float* b_hh    = (const float*)d_in[11];

    char* ws = (char*)d_ws;
    float* hid = (float*)(ws + WS_HID);
    float* ctx = (float*)(ws + WS_CTX);
    int4*  Wbf = (int4*)(ws + WS_WBF);

    float* out = (float*)d_out;
    float* alpha = out + 131072;            // h:[0,64K) c:[64K,128K) alpha:[128K,256K) floats

    hipLaunchKernelGGL(k_prep,       dim3(288),   dim3(256), 0, stream,
                       prev_h, W_i2h, W_h2h, b_h2h, hid, Wbf);
    hipLaunchKernelGGL(k_attn,       dim3(256),   dim3(512), 0, stream,
                       batch_H, Wbf, hid, W_score, alpha, ctx);
    hipLaunchKernelGGL(k_gates_lstm, dim3(4, 16), dim3(256), 0, stream,
                       ctx, onehot, prev_h, W_ih, W_hh, b_ih, b_hh, prev_c, out);
}